// Round 14
// baseline (157.952 us; speedup 1.0000x reference)
//
#include <hip/hip_runtime.h>

// VQ-VAE VectorQuantizer fwd. K=1024, E=64, N=T*B=65536.
// bf16-split MFMA argmin (gap<6e-6 flagged) -> fp64 exact re-resolve.
// Scores t = ||c||^2 - 2 x.c; codebook pre-scaled by -2, ||c||^2 in C-init.
// MFMA: A = codebook frag, B = x frag -> D(lane l, reg r) =
// score(code = t*16 + (l>>4)*4 + r, row = base + (l&15)).
// R14: (a) stream dedup -- old record chunks j=4,5 were byte-identical to
// j=0,1 (ch paired with xh AND xl); record now 4 frags + ||c||^2 = 5KB
// (-29% stream, 5 loads/tile), MFMA reuses b0,b1 for the xl terms.
// (b) R11 shape (1024 thr, 4rg x 4kh, rpw=64, xq resident ~64 VGPR; R13's
// rpw=128 fell over the register cliff -> per-tile LDS re-reads) + explicit
// 2-deep even/odd register pipeline on the b-stream (~125 VGPR total).
// (c) R13's fused pipeline kept: 4 launches, SSE via d^2 = best + ||x||^2.

#define KC 1024
#define ED 64
#define NR 65536
#define NE (NR * ED)
#define GAP1 6e-6f

typedef __attribute__((ext_vector_type(8))) short short8;
typedef __attribute__((ext_vector_type(4))) float f32x4;

__device__ __forceinline__ unsigned short bf16rne(float f) {
    unsigned u = __builtin_bit_cast(unsigned, f);
    return (unsigned short)((u + 0x7fffu + ((u >> 16) & 1u)) >> 16);
}
__device__ __forceinline__ float bf16tof(unsigned short h) {
    return __builtin_bit_cast(float, (unsigned)h << 16);
}

// Pack compact tile records (stride 320 short8 = 5KB) + zero counts/flag.
// Record t: j=0,1 = ch (hi bf16 of -2*c) for e in [0,32),[32,64); j=2,3 =
// cl (lo residual); elem (g=l>>4,r) <-> e = (j&1)*32 + g*8 + r (same
// bijection as the x fragments); j=4: f32x4 ||c||^2 (reg r <-> code
// t*16+(l>>4)*4+r) bitcast short8.
__global__ __launch_bounds__(256) void k_pack(const float* __restrict__ cb,
        short8* __restrict__ cbt, unsigned* __restrict__ counts,
        unsigned* __restrict__ flagcnt) {
    const int u = blockIdx.x * 256 + threadIdx.x;
    if (u < 1024) counts[u] = 0u;
    if (u == 1024) *flagcnt = 0u;
    if (u >= 64 * 5 * 64) return;
    const int t = u / 320, rem = u % 320, j = rem / 64, l = rem % 64;
    const int g = l >> 4;
    if (j < 4) {
        const int code = t * 16 + (l & 15);
        const float* c = cb + (size_t)code * ED;
        const bool lo = (j >= 2);
        short8 o;
#pragma unroll
        for (int r = 0; r < 8; ++r) {
            const int e = (j & 1) * 32 + g * 8 + r;
            const float m2 = -2.f * c[e];
            const unsigned short h = bf16rne(m2);
            o[r] = lo ? (short)bf16rne(m2 - bf16tof(h)) : (short)h;
        }
        cbt[u] = o;
    } else {
        f32x4 o;
#pragma unroll
        for (int r = 0; r < 4; ++r) {
            const float4* c4 = (const float4*)(cb + (size_t)(t * 16 + g * 4 + r) * ED);
            float s0 = 0.f, s1 = 0.f, s2 = 0.f, s3 = 0.f;
#pragma unroll
            for (int i = 0; i < 16; ++i) {
                const float4 c = c4[i];
                s0 = fmaf(c.x, c.x, s0); s1 = fmaf(c.y, c.y, s1);
                s2 = fmaf(c.z, c.z, s2); s3 = fmaf(c.w, c.w, s3);
            }
            o[r] = (s0 + s1) + (s2 + s3);
        }
        cbt[u] = __builtin_bit_cast(short8, o);
    }
}

// 256 blocks x 1024 thr (16 waves = 4 row-groups x 4 K-quarters), 256 rows
// per block, 64 rows/wave. Phase 1: cooperative x -> bf16 hi/lo frags into
// LDS + ||x||^2 partials. Phase 2: wave (rg,kh) holds its 16 x-frags in 64
// VGPR, scans tiles [kh*16,+16) with a 2-deep even/odd register pipeline on
// the 5-load tile records. Phase 3: shfl g-merge; waves 0-3 merge kh slices
// (ascending == k-ascending tie-break), write idx/histogram/flag/SSE.
__global__ __launch_bounds__(1024) void k_argmin(
        const float* __restrict__ in, const short8* __restrict__ cbt,
        int* __restrict__ idx, unsigned* __restrict__ counts,
        unsigned* __restrict__ flagcnt, unsigned* __restrict__ flaglist,
        double* __restrict__ pblk) {
    __shared__ short8 xs[4][16][64];              // 64 KB
    __shared__ float rx2p[4][256];                // 4 KB
    __shared__ float sb[16][4][16], sb2[16][4][16];
    __shared__ int   sk[16][4][16];               // 12 KB
    __shared__ double sred[4];

    const int tid = threadIdx.x;
    const int l = tid & 63;
    const int wid = tid >> 6;                     // 0..15
    const int g = l >> 4;
    const int col = l & 15;
    const int rowBase = blockIdx.x * 256;

    // Phase 1: thread (row=tid&255, ob=tid>>8) converts octs {ob, ob+4}
    // (16 elems) of its row; ll = ob*16 + (row&15), slot = rt*4 + hh (+2 lo).
    {
        const int row = tid & 255;
        const int ob = tid >> 8;                  // 0..3 (== g of the frag)
        const int rg = row >> 6;
        const int r6 = row & 63;
        const int rt = r6 >> 4;
        const int ll = ob * 16 + (r6 & 15);
        float part = 0.f;
#pragma unroll
        for (int hh = 0; hh < 2; ++hh) {
            const int oct = ob + hh * 4;
            short8 H, L;
#pragma unroll
            for (int j = 0; j < 8; ++j) {
                const float x = in[(size_t)(oct * 8 + j) * NR + rowBase + row];
                const unsigned short hb = bf16rne(x);
                H[j] = (short)hb;
                L[j] = (short)bf16rne(x - bf16tof(hb));
                part = fmaf(x, x, part);
            }
            xs[rg][rt * 4 + hh][ll] = H;
            xs[rg][rt * 4 + 2 + hh][ll] = L;
        }
        rx2p[ob][row] = part;
    }
    __syncthreads();

    // Phase 2: x frags to regs (resident), pipelined K-quarter scan.
    const int rg = wid >> 2, kh = wid & 3;
    short8 xq[4][4];
#pragma unroll
    for (int rt = 0; rt < 4; ++rt)
#pragma unroll
        for (int q = 0; q < 4; ++q)
            xq[rt][q] = xs[rg][rt * 4 + q][l];

    float best[4]  = {3.4e38f, 3.4e38f, 3.4e38f, 3.4e38f};
    float best2[4] = {3.4e38f, 3.4e38f, 3.4e38f, 3.4e38f};
    int bestk[4] = {0, 0, 0, 0};

    const int t0 = kh * 16;

#define LOADT(P, T) do { \
        const short8* bp_ = cbt + (size_t)(T) * 320 + l; \
        P##0 = bp_[0];   P##1 = bp_[64]; \
        P##2 = bp_[128]; P##3 = bp_[192]; \
        P##e = __builtin_bit_cast(f32x4, bp_[256]); \
    } while (0)

#define COMPT(P, T) do { \
        _Pragma("unroll") \
        for (int rt_ = 0; rt_ < 4; ++rt_) { \
            f32x4 acc_ = P##e; \
            acc_ = __builtin_amdgcn_mfma_f32_16x16x32_bf16(P##0, xq[rt_][0], acc_, 0, 0, 0); \
            acc_ = __builtin_amdgcn_mfma_f32_16x16x32_bf16(P##1, xq[rt_][1], acc_, 0, 0, 0); \
            acc_ = __builtin_amdgcn_mfma_f32_16x16x32_bf16(P##2, xq[rt_][0], acc_, 0, 0, 0); \
            acc_ = __builtin_amdgcn_mfma_f32_16x16x32_bf16(P##3, xq[rt_][1], acc_, 0, 0, 0); \
            acc_ = __builtin_amdgcn_mfma_f32_16x16x32_bf16(P##0, xq[rt_][2], acc_, 0, 0, 0); \
            acc_ = __builtin_amdgcn_mfma_f32_16x16x32_bf16(P##1, xq[rt_][3], acc_, 0, 0, 0); \
            _Pragma("unroll") \
            for (int r_ = 0; r_ < 4; ++r_) { \
                const float v_ = acc_[r_]; \
                const int k_ = (T) * 16 + g * 4 + r_; \
                best2[rt_] = fminf(fmaxf(v_, best[rt_]), best2[rt_]); \
                const bool c_ = v_ < best[rt_]; \
                bestk[rt_] = c_ ? k_ : bestk[rt_]; \
                best[rt_]  = fminf(v_, best[rt_]); \
            } \
        } \
    } while (0)

    short8 A0, A1, A2, A3; f32x4 Ae;
    short8 B0, B1, B2, B3; f32x4 Be;
    LOADT(A, t0);
#pragma unroll
    for (int p = 0; p < 8; ++p) {
        LOADT(B, t0 + 2 * p + 1);
        COMPT(A, t0 + 2 * p);
        if (p < 7) LOADT(A, t0 + 2 * p + 2);
        COMPT(B, t0 + 2 * p + 1);
    }
#undef LOADT
#undef COMPT

    // Phase 3a: intra-wave g-merge; g==0 writes per-(rg,kh) partials.
#pragma unroll
    for (int rt = 0; rt < 4; ++rt) {
        float b = best[rt], b2 = best2[rt]; int k = bestk[rt];
#pragma unroll
        for (int sh = 16; sh <= 32; sh <<= 1) {
            const float ob  = __shfl_xor(b, sh, 64);
            const float ob2 = __shfl_xor(b2, sh, 64);
            const int   ok  = __shfl_xor(k, sh, 64);
            if (ob < b || (ob == b && ok < k)) { b2 = fminf(b, ob2); k = ok; b = ob; }
            else b2 = fminf(b2, ob);
        }
        if (g == 0) { sb[wid][rt][col] = b; sb2[wid][rt][col] = b2; sk[wid][rt][col] = k; }
    }
    __syncthreads();

    // Phase 3b: waves 0-3 (rg=wid) merge the 4 kh slices; finalize rows.
    if (wid < 4) {
        const int rt = l >> 4, c2 = l & 15;
        float b = sb[wid * 4][rt][c2], b2 = sb2[wid * 4][rt][c2];
        int k = sk[wid * 4][rt][c2];
#pragma unroll
        for (int s = 1; s < 4; ++s) {              // ascending k ranges
            const float ob = sb[wid * 4 + s][rt][c2], ob2 = sb2[wid * 4 + s][rt][c2];
            const int ok = sk[wid * 4 + s][rt][c2];
            if (ob < b || (ob == b && ok < k)) { b2 = fminf(b, ob2); k = ok; b = ob; }
            else b2 = fminf(b2, ob);
        }
        const int lrow = wid * 64 + rt * 16 + c2;
        const int row = rowBase + lrow;
        idx[row] = k;
        atomicAdd(&counts[k], 1u);
        if (b2 - b < GAP1) {
            const unsigned p = atomicAdd(flagcnt, 1u);
            flaglist[p] = (unsigned)row;
        }
        double d2 = (double)b + (double)((rx2p[0][lrow] + rx2p[1][lrow])
                                       + (rx2p[2][lrow] + rx2p[3][lrow]));
#pragma unroll
        for (int off = 32; off > 0; off >>= 1) d2 += __shfl_down(d2, off, 64);
        if (l == 0) sred[wid] = d2;
    }
    __syncthreads();
    if (tid == 0)
        pblk[blockIdx.x] = (sred[0] + sred[1]) + (sred[2] + sred[3]);
}

// fp64 exact argmin for flagged rows; one wave per row; adjusts histogram
// when the index changes. (SSE delta < GAP1 per flipped row -> negligible.)
__global__ __launch_bounds__(256) void k_exact64(
        const float* __restrict__ in, const float* __restrict__ cb,
        int* __restrict__ idx, unsigned* __restrict__ counts,
        const unsigned* __restrict__ flagcnt, const unsigned* __restrict__ flaglist) {
    const unsigned nf = *flagcnt;
    const int l = threadIdx.x & 63;
    const unsigned wave = blockIdx.x * 4u + (unsigned)(threadIdx.x >> 6);
    const unsigned nwave = gridDim.x * 4u;
    for (unsigned i = wave; i < nf; i += nwave) {
        const int row = (int)flaglist[i];
        float x[ED];
#pragma unroll
        for (int e = 0; e < ED; ++e) x[e] = in[(size_t)e * NR + row];
        double best = 1e300; int bestk = 0;
        for (int ci = 0; ci < 16; ++ci) {
            const int k = ci * 64 + l;              // ascending k per lane
            const float* c = cb + (size_t)k * ED;
            double s = 0.0, e2 = 0.0;
            for (int e = 0; e < ED; ++e) {
                const double cv = (double)c[e];
                e2 = fma(cv, cv, e2);
                s  = fma(cv, (double)x[e], s);
            }
            const double t = fma(-2.0, s, e2);
            if (t < best) { best = t; bestk = k; }
        }
        for (int sh = 1; sh < 64; sh <<= 1) {
            const double ob = __shfl_xor(best, sh, 64);
            const int   ok  = __shfl_xor(bestk, sh, 64);
            if (ob < best || (ob == best && ok < bestk)) { best = ob; bestk = ok; }
        }
        if (l == 0) {
            const int old = idx[row];
            if (bestk != old) {
                idx[row] = bestk;
                atomicSub(&counts[old], 1u);
                atomicAdd(&counts[bestk], 1u);
            }
        }
    }
}

// Gather qout[e][n] = cb[idx[n]][e]; block 0 additionally computes the two
// scalars (entropy from counts, SSE from 256 pblk partials), both finalized
// before this launch; fixed-order reduce -> deterministic.
__global__ __launch_bounds__(256) void k_output(
        const float* __restrict__ cb, const int* __restrict__ idx,
        float* __restrict__ qout, const unsigned* __restrict__ counts,
        const double* __restrict__ pblk, float* __restrict__ out) {
    const int gtid = blockIdx.x * 256 + threadIdx.x;
    const int n = gtid & (NR - 1);
    const int e0 = gtid >> 16;                      // 0..7
    const int k = idx[n];
    const float4* c4 = (const float4*)(cb + (size_t)k * ED + e0 * 8);
    const float4 q0 = c4[0], q1 = c4[1];
#pragma unroll
    for (int j = 0; j < 8; ++j) {
        const float q = (j < 4) ? ((const float*)&q0)[j] : ((const float*)&q1)[j - 4];
        qout[(size_t)(e0 * 8 + j) * NR + n] = q;
    }
    if (blockIdx.x == 0) {
        __shared__ double redE[4], redS[4];
        const int tid = threadIdx.x;
        double term = 0.0;
#pragma unroll
        for (int i = 0; i < 4; ++i) {
            const double p = (double)counts[tid + i * 256] * (1.0 / 65536.0);
            term += p * log(p + 1e-10);
        }
        double s = pblk[tid];
#pragma unroll
        for (int off = 32; off > 0; off >>= 1) {
            term += __shfl_down(term, off, 64);
            s    += __shfl_down(s,    off, 64);
        }
        if ((tid & 63) == 0) { redE[tid >> 6] = term; redS[tid >> 6] = s; }
        __syncthreads();
        if (tid == 0) {
            const double e = (redE[0] + redE[1]) + (redE[2] + redE[3]);
            const double ss = (redS[0] + redS[1]) + (redS[2] + redS[3]);
            out[1 + NE] = (float)exp(-e);             // perplexity
            const double m = ss * (1.0 / 4194304.0);  // mean((q-x)^2)
            out[0] = (float)(1.25 * m);               // (1+beta)*m
        }
    }
}

extern "C" void kernel_launch(void* const* d_in, const int* in_sizes, int n_in,
                              void* d_out, int out_size, void* d_ws, size_t ws_size,
                              hipStream_t stream) {
    (void)in_sizes; (void)n_in; (void)out_size; (void)ws_size;
    const float* in = (const float*)d_in[0];
    const float* cb = (const float*)d_in[1];
    float* out = (float*)d_out;

    // ws layout (dword offsets), strictly disjoint:
    //  [0,1024) counts | [1024] flagcnt
    //  [2048,83968)   cbt: 64 tiles x 320 short8 (compact 5KB records)
    //  [83968,149504) idx | [149504,215040) flaglist
    //  pblk: 256 f64 at byte 991232 (8B-aligned)
    unsigned* counts   = (unsigned*)d_ws;
    unsigned* flagcnt  = (unsigned*)d_ws + 1024;
    short8*   cbt      = (short8*)((float*)d_ws + 2048);
    int*      idx      = (int*)d_ws + 83968;
    unsigned* flaglist = (unsigned*)d_ws + 149504;
    double*   pblk     = (double*)((char*)d_ws + 991232);

    hipLaunchKernelGGL(k_pack,    dim3(80),   dim3(256),  0, stream,
                       cb, cbt, counts, flagcnt);
    hipLaunchKernelGGL(k_argmin,  dim3(256),  dim3(1024), 0, stream,
                       in, cbt, idx, counts, flagcnt, flaglist, pblk);
    hipLaunchKernelGGL(k_exact64, dim3(128),  dim3(256),  0, stream,
                       in, cb, idx, counts, flagcnt, flaglist);
    hipLaunchKernelGGL(k_output,  dim3(2048), dim3(256),  0, stream,
                       cb, idx, out + 1, counts, pblk, out);
}

// Round 15
// 86.245 us; speedup vs baseline: 1.8314x; 1.8314x over previous
//
#include <hip/hip_runtime.h>

// VQ-VAE VectorQuantizer fwd. K=1024, E=64, N=T*B=65536.
// bf16-split MFMA argmin (gap<6e-6 flagged) -> fp64 exact re-resolve.
// Scores t = ||c||^2 - 2 x.c; codebook pre-scaled by -2, ||c||^2 in C-init.
// MFMA: A = codebook frag, B = x frag -> D(lane l, reg r) =
// score(code = t*16 + (l>>4)*4 + r, row = base + (l&15)).
// R15: revert R14's explicit even/odd register pipeline (the spill trigger:
// 1024-thr blocks get a 64-VGPR default budget; the pipeline's live set
// blew it -> WRITE_SIZE 210MB scratch). Back to R11's simple per-tile loop
// (compiler rematerializes xq from LDS within 64 VGPR; R11 measured best,
// <=40us). KEPT from R14: dedup'd 5KB tile records (ch reused for xh and
// xl terms, -29% stream) + fused idx/histogram/flag/SSE epilogue, 4 launches.

#define KC 1024
#define ED 64
#define NR 65536
#define NE (NR * ED)
#define GAP1 6e-6f

typedef __attribute__((ext_vector_type(8))) short short8;
typedef __attribute__((ext_vector_type(4))) float f32x4;

__device__ __forceinline__ unsigned short bf16rne(float f) {
    unsigned u = __builtin_bit_cast(unsigned, f);
    return (unsigned short)((u + 0x7fffu + ((u >> 16) & 1u)) >> 16);
}
__device__ __forceinline__ float bf16tof(unsigned short h) {
    return __builtin_bit_cast(float, (unsigned)h << 16);
}

// Pack compact tile records (stride 320 short8 = 5KB) + zero counts/flag.
// Record t: j=0,1 = ch (hi bf16 of -2*c) for e in [0,32),[32,64); j=2,3 =
// cl (lo residual); elem (g=l>>4,r) <-> e = (j&1)*32 + g*8 + r (same
// bijection as the x fragments); j=4: f32x4 ||c||^2 (reg r <-> code
// t*16+(l>>4)*4+r) bitcast short8.
__global__ __launch_bounds__(256) void k_pack(const float* __restrict__ cb,
        short8* __restrict__ cbt, unsigned* __restrict__ counts,
        unsigned* __restrict__ flagcnt) {
    const int u = blockIdx.x * 256 + threadIdx.x;
    if (u < 1024) counts[u] = 0u;
    if (u == 1024) *flagcnt = 0u;
    if (u >= 64 * 5 * 64) return;
    const int t = u / 320, rem = u % 320, j = rem / 64, l = rem % 64;
    const int g = l >> 4;
    if (j < 4) {
        const int code = t * 16 + (l & 15);
        const float* c = cb + (size_t)code * ED;
        const bool lo = (j >= 2);
        short8 o;
#pragma unroll
        for (int r = 0; r < 8; ++r) {
            const int e = (j & 1) * 32 + g * 8 + r;
            const float m2 = -2.f * c[e];
            const unsigned short h = bf16rne(m2);
            o[r] = lo ? (short)bf16rne(m2 - bf16tof(h)) : (short)h;
        }
        cbt[u] = o;
    } else {
        f32x4 o;
#pragma unroll
        for (int r = 0; r < 4; ++r) {
            const float4* c4 = (const float4*)(cb + (size_t)(t * 16 + g * 4 + r) * ED);
            float s0 = 0.f, s1 = 0.f, s2 = 0.f, s3 = 0.f;
#pragma unroll
            for (int i = 0; i < 16; ++i) {
                const float4 c = c4[i];
                s0 = fmaf(c.x, c.x, s0); s1 = fmaf(c.y, c.y, s1);
                s2 = fmaf(c.z, c.z, s2); s3 = fmaf(c.w, c.w, s3);
            }
            o[r] = (s0 + s1) + (s2 + s3);
        }
        cbt[u] = __builtin_bit_cast(short8, o);
    }
}

// 256 blocks x 1024 thr (16 waves = 4 row-groups x 4 K-quarters), 256 rows
// per block, 64 rows/wave. Phase 1: cooperative x -> bf16 hi/lo frags into
// LDS + ||x||^2 partials. Phase 2: wave (rg,kh) scans tiles [kh*16,+16),
// simple loop, 5 loads + 24 MFMA + min-track per tile (b0,b1 reused for the
// xl terms). Phase 3: shfl g-merge; waves 0-3 merge kh slices (ascending ==
// k-ascending tie-break), write idx/histogram/flag/SSE (d^2 = best+||x||^2).
__global__ __launch_bounds__(1024) void k_argmin(
        const float* __restrict__ in, const short8* __restrict__ cbt,
        int* __restrict__ idx, unsigned* __restrict__ counts,
        unsigned* __restrict__ flagcnt, unsigned* __restrict__ flaglist,
        double* __restrict__ pblk) {
    __shared__ short8 xs[4][16][64];              // 64 KB
    __shared__ float rx2p[4][256];                // 4 KB
    __shared__ float sb[16][4][16], sb2[16][4][16];
    __shared__ int   sk[16][4][16];               // 12 KB
    __shared__ double sred[4];

    const int tid = threadIdx.x;
    const int l = tid & 63;
    const int wid = tid >> 6;                     // 0..15
    const int g = l >> 4;
    const int col = l & 15;
    const int rowBase = blockIdx.x * 256;

    // Phase 1: thread (row=tid&255, ob=tid>>8) converts octs {ob, ob+4}
    // (16 elems) of its row; ll = ob*16 + (row&15), slot = rt*4 + hh (+2 lo).
    {
        const int row = tid & 255;
        const int ob = tid >> 8;                  // 0..3 (== g of the frag)
        const int rg = row >> 6;
        const int r6 = row & 63;
        const int rt = r6 >> 4;
        const int ll = ob * 16 + (r6 & 15);
        float part = 0.f;
#pragma unroll
        for (int hh = 0; hh < 2; ++hh) {
            const int oct = ob + hh * 4;
            short8 H, L;
#pragma unroll
            for (int j = 0; j < 8; ++j) {
                const float x = in[(size_t)(oct * 8 + j) * NR + rowBase + row];
                const unsigned short hb = bf16rne(x);
                H[j] = (short)hb;
                L[j] = (short)bf16rne(x - bf16tof(hb));
                part = fmaf(x, x, part);
            }
            xs[rg][rt * 4 + hh][ll] = H;
            xs[rg][rt * 4 + 2 + hh][ll] = L;
        }
        rx2p[ob][row] = part;
    }
    __syncthreads();

    // Phase 2: simple per-tile loop (R11 shape). xq staged; compiler may
    // rematerialize from LDS under the 64-VGPR budget -- that's fine.
    const int rg = wid >> 2, kh = wid & 3;
    short8 xq[4][4];
#pragma unroll
    for (int rt = 0; rt < 4; ++rt)
#pragma unroll
        for (int q = 0; q < 4; ++q)
            xq[rt][q] = xs[rg][rt * 4 + q][l];

    float best[4]  = {3.4e38f, 3.4e38f, 3.4e38f, 3.4e38f};
    float best2[4] = {3.4e38f, 3.4e38f, 3.4e38f, 3.4e38f};
    int bestk[4] = {0, 0, 0, 0};

#pragma unroll 2
    for (int tt = 0; tt < 16; ++tt) {
        const int t = kh * 16 + tt;
        const short8* bp = cbt + (size_t)t * 320 + l;
        const short8 b0 = bp[0], b1 = bp[64], b2 = bp[128], b3 = bp[192];
        const f32x4 e4 = __builtin_bit_cast(f32x4, bp[256]);
#pragma unroll
        for (int rt = 0; rt < 4; ++rt) {
            f32x4 acc = e4;
            acc = __builtin_amdgcn_mfma_f32_16x16x32_bf16(b0, xq[rt][0], acc, 0, 0, 0);
            acc = __builtin_amdgcn_mfma_f32_16x16x32_bf16(b1, xq[rt][1], acc, 0, 0, 0);
            acc = __builtin_amdgcn_mfma_f32_16x16x32_bf16(b2, xq[rt][0], acc, 0, 0, 0);
            acc = __builtin_amdgcn_mfma_f32_16x16x32_bf16(b3, xq[rt][1], acc, 0, 0, 0);
            acc = __builtin_amdgcn_mfma_f32_16x16x32_bf16(b0, xq[rt][2], acc, 0, 0, 0);
            acc = __builtin_amdgcn_mfma_f32_16x16x32_bf16(b1, xq[rt][3], acc, 0, 0, 0);
#pragma unroll
            for (int r = 0; r < 4; ++r) {
                const float v = acc[r];
                const int k = t * 16 + g * 4 + r;
                best2[rt] = fminf(fmaxf(v, best[rt]), best2[rt]);  // med3
                const bool c = v < best[rt];
                bestk[rt] = c ? k : bestk[rt];
                best[rt]  = fminf(v, best[rt]);
            }
        }
    }

    // Phase 3a: intra-wave g-merge; g==0 writes per-(rg,kh) partials.
#pragma unroll
    for (int rt = 0; rt < 4; ++rt) {
        float b = best[rt], b2 = best2[rt]; int k = bestk[rt];
#pragma unroll
        for (int sh = 16; sh <= 32; sh <<= 1) {
            const float ob  = __shfl_xor(b, sh, 64);
            const float ob2 = __shfl_xor(b2, sh, 64);
            const int   ok  = __shfl_xor(k, sh, 64);
            if (ob < b || (ob == b && ok < k)) { b2 = fminf(b, ob2); k = ok; b = ob; }
            else b2 = fminf(b2, ob);
        }
        if (g == 0) { sb[wid][rt][col] = b; sb2[wid][rt][col] = b2; sk[wid][rt][col] = k; }
    }
    __syncthreads();

    // Phase 3b: waves 0-3 (rg=wid) merge the 4 kh slices; finalize rows.
    if (wid < 4) {
        const int rt = l >> 4, c2 = l & 15;
        float b = sb[wid * 4][rt][c2], b2 = sb2[wid * 4][rt][c2];
        int k = sk[wid * 4][rt][c2];
#pragma unroll
        for (int s = 1; s < 4; ++s) {              // ascending k ranges
            const float ob = sb[wid * 4 + s][rt][c2], ob2 = sb2[wid * 4 + s][rt][c2];
            const int ok = sk[wid * 4 + s][rt][c2];
            if (ob < b || (ob == b && ok < k)) { b2 = fminf(b, ob2); k = ok; b = ob; }
            else b2 = fminf(b2, ob);
        }
        const int lrow = wid * 64 + rt * 16 + c2;
        const int row = rowBase + lrow;
        idx[row] = k;
        atomicAdd(&counts[k], 1u);
        if (b2 - b < GAP1) {
            const unsigned p = atomicAdd(flagcnt, 1u);
            flaglist[p] = (unsigned)row;
        }
        double d2 = (double)b + (double)((rx2p[0][lrow] + rx2p[1][lrow])
                                       + (rx2p[2][lrow] + rx2p[3][lrow]));
#pragma unroll
        for (int off = 32; off > 0; off >>= 1) d2 += __shfl_down(d2, off, 64);
        if (l == 0) sred[wid] = d2;
    }
    __syncthreads();
    if (tid == 0)
        pblk[blockIdx.x] = (sred[0] + sred[1]) + (sred[2] + sred[3]);
}

// fp64 exact argmin for flagged rows; one wave per row; adjusts histogram
// when the index changes. (SSE delta < GAP1 per flipped row -> negligible.)
__global__ __launch_bounds__(256) void k_exact64(
        const float* __restrict__ in, const float* __restrict__ cb,
        int* __restrict__ idx, unsigned* __restrict__ counts,
        const unsigned* __restrict__ flagcnt, const unsigned* __restrict__ flaglist) {
    const unsigned nf = *flagcnt;
    const int l = threadIdx.x & 63;
    const unsigned wave = blockIdx.x * 4u + (unsigned)(threadIdx.x >> 6);
    const unsigned nwave = gridDim.x * 4u;
    for (unsigned i = wave; i < nf; i += nwave) {
        const int row = (int)flaglist[i];
        float x[ED];
#pragma unroll
        for (int e = 0; e < ED; ++e) x[e] = in[(size_t)e * NR + row];
        double best = 1e300; int bestk = 0;
        for (int ci = 0; ci < 16; ++ci) {
            const int k = ci * 64 + l;              // ascending k per lane
            const float* c = cb + (size_t)k * ED;
            double s = 0.0, e2 = 0.0;
            for (int e = 0; e < ED; ++e) {
                const double cv = (double)c[e];
                e2 = fma(cv, cv, e2);
                s  = fma(cv, (double)x[e], s);
            }
            const double t = fma(-2.0, s, e2);
            if (t < best) { best = t; bestk = k; }
        }
        for (int sh = 1; sh < 64; sh <<= 1) {
            const double ob = __shfl_xor(best, sh, 64);
            const int   ok  = __shfl_xor(bestk, sh, 64);
            if (ob < best || (ob == best && ok < bestk)) { best = ob; bestk = ok; }
        }
        if (l == 0) {
            const int old = idx[row];
            if (bestk != old) {
                idx[row] = bestk;
                atomicSub(&counts[old], 1u);
                atomicAdd(&counts[bestk], 1u);
            }
        }
    }
}

// Gather qout[e][n] = cb[idx[n]][e]; block 0 additionally computes the two
// scalars (entropy from counts, SSE from 256 pblk partials), both finalized
// before this launch; fixed-order reduce -> deterministic.
__global__ __launch_bounds__(256) void k_output(
        const float* __restrict__ cb, const int* __restrict__ idx,
        float* __restrict__ qout, const unsigned* __restrict__ counts,
        const double* __restrict__ pblk, float* __restrict__ out) {
    const int gtid = blockIdx.x * 256 + threadIdx.x;
    const int n = gtid & (NR - 1);
    const int e0 = gtid >> 16;                      // 0..7
    const int k = idx[n];
    const float4* c4 = (const float4*)(cb + (size_t)k * ED + e0 * 8);
    const float4 q0 = c4[0], q1 = c4[1];
#pragma unroll
    for (int j = 0; j < 8; ++j) {
        const float q = (j < 4) ? ((const float*)&q0)[j] : ((const float*)&q1)[j - 4];
        qout[(size_t)(e0 * 8 + j) * NR + n] = q;
    }
    if (blockIdx.x == 0) {
        __shared__ double redE[4], redS[4];
        const int tid = threadIdx.x;
        double term = 0.0;
#pragma unroll
        for (int i = 0; i < 4; ++i) {
            const double p = (double)counts[tid + i * 256] * (1.0 / 65536.0);
            term += p * log(p + 1e-10);
        }
        double s = pblk[tid];
#pragma unroll
        for (int off = 32; off > 0; off >>= 1) {
            term += __shfl_down(term, off, 64);
            s    += __shfl_down(s,    off, 64);
        }
        if ((tid & 63) == 0) { redE[tid >> 6] = term; redS[tid >> 6] = s; }
        __syncthreads();
        if (tid == 0) {
            const double e = (redE[0] + redE[1]) + (redE[2] + redE[3]);
            const double ss = (redS[0] + redS[1]) + (redS[2] + redS[3]);
            out[1 + NE] = (float)exp(-e);             // perplexity
            const double m = ss * (1.0 / 4194304.0);  // mean((q-x)^2)
            out[0] = (float)(1.25 * m);               // (1+beta)*m
        }
    }
}

extern "C" void kernel_launch(void* const* d_in, const int* in_sizes, int n_in,
                              void* d_out, int out_size, void* d_ws, size_t ws_size,
                              hipStream_t stream) {
    (void)in_sizes; (void)n_in; (void)out_size; (void)ws_size;
    const float* in = (const float*)d_in[0];
    const float* cb = (const float*)d_in[1];
    float* out = (float*)d_out;

    // ws layout (dword offsets), strictly disjoint:
    //  [0,1024) counts | [1024] flagcnt
    //  [2048,83968)   cbt: 64 tiles x 320 short8 (compact 5KB records)
    //  [83968,149504) idx | [149504,215040) flaglist
    //  pblk: 256 f64 at byte 991232 (8B-aligned)
    unsigned* counts   = (unsigned*)d_ws;
    unsigned* flagcnt  = (unsigned*)d_ws + 1024;
    short8*   cbt      = (short8*)((float*)d_ws + 2048);
    int*      idx      = (int*)d_ws + 83968;
    unsigned* flaglist = (unsigned*)d_ws + 149504;
    double*   pblk     = (double*)((char*)d_ws + 991232);

    hipLaunchKernelGGL(k_pack,    dim3(80),   dim3(256),  0, stream,
                       cb, cbt, counts, flagcnt);
    hipLaunchKernelGGL(k_argmin,  dim3(256),  dim3(1024), 0, stream,
                       in, cbt, idx, counts, flagcnt, flaglist, pblk);
    hipLaunchKernelGGL(k_exact64, dim3(128),  dim3(256),  0, stream,
                       in, cb, idx, counts, flagcnt, flaglist);
    hipLaunchKernelGGL(k_output,  dim3(2048), dim3(256),  0, stream,
                       cb, idx, out + 1, counts, pblk, out);
}

// Round 16
// 81.247 us; speedup vs baseline: 1.9441x; 1.0615x over previous
//
#include <hip/hip_runtime.h>

// VQ-VAE VectorQuantizer fwd. K=1024, E=64, N=T*B=65536.
// bf16-split MFMA argmin (gap<6e-6 flagged) -> fp64 exact re-resolve.
// Scores t = ||c||^2 - 2 x.c; codebook pre-scaled by -2, ||c||^2 in C-init.
// MFMA: A = codebook frag, B = x frag -> D(lane l, reg r) =
// score(code = t*16 + (l>>4)*4 + r, row = base + (l&15)).
// R16: (a) 512-thr blocks (measured ~116-VGPR budget vs 1024-thr's 60) so
// the 64-VGPR xq set can be RESIDENT -- R15's 60-reg budget forced ~4096
// ds_read_b128/CU of per-tile rematerialization (~20us of LDS port time).
// 512 blocks x (2rg x 4kh waves), 128 rows/block, exactly 2 blocks/CU (no
// tail round). (b) k_output eliminated: phase-4 cooperative gather in
// k_argmin writes qout from the LDS-resident final idx; k_exact64 rewrites
// flipped rows; 1-block k_final does the scalars.

#define KC 1024
#define ED 64
#define NR 65536
#define NE (NR * ED)
#define GAP1 6e-6f

typedef __attribute__((ext_vector_type(8))) short short8;
typedef __attribute__((ext_vector_type(4))) float f32x4;

__device__ __forceinline__ unsigned short bf16rne(float f) {
    unsigned u = __builtin_bit_cast(unsigned, f);
    return (unsigned short)((u + 0x7fffu + ((u >> 16) & 1u)) >> 16);
}
__device__ __forceinline__ float bf16tof(unsigned short h) {
    return __builtin_bit_cast(float, (unsigned)h << 16);
}

// Pack compact tile records (stride 320 short8 = 5KB) + zero counts/flag.
// Record t: j=0,1 = ch (hi bf16 of -2*c) for e in [0,32),[32,64); j=2,3 =
// cl (lo residual); elem (g=l>>4,r) <-> e = (j&1)*32 + g*8 + r (same
// bijection as the x fragments); j=4: f32x4 ||c||^2 (reg r <-> code
// t*16+(l>>4)*4+r) bitcast short8.
__global__ __launch_bounds__(256) void k_pack(const float* __restrict__ cb,
        short8* __restrict__ cbt, unsigned* __restrict__ counts,
        unsigned* __restrict__ flagcnt) {
    const int u = blockIdx.x * 256 + threadIdx.x;
    if (u < 1024) counts[u] = 0u;
    if (u == 1024) *flagcnt = 0u;
    if (u >= 64 * 5 * 64) return;
    const int t = u / 320, rem = u % 320, j = rem / 64, l = rem % 64;
    const int g = l >> 4;
    if (j < 4) {
        const int code = t * 16 + (l & 15);
        const float* c = cb + (size_t)code * ED;
        const bool lo = (j >= 2);
        short8 o;
#pragma unroll
        for (int r = 0; r < 8; ++r) {
            const int e = (j & 1) * 32 + g * 8 + r;
            const float m2 = -2.f * c[e];
            const unsigned short h = bf16rne(m2);
            o[r] = lo ? (short)bf16rne(m2 - bf16tof(h)) : (short)h;
        }
        cbt[u] = o;
    } else {
        f32x4 o;
#pragma unroll
        for (int r = 0; r < 4; ++r) {
            const float4* c4 = (const float4*)(cb + (size_t)(t * 16 + g * 4 + r) * ED);
            float s0 = 0.f, s1 = 0.f, s2 = 0.f, s3 = 0.f;
#pragma unroll
            for (int i = 0; i < 16; ++i) {
                const float4 c = c4[i];
                s0 = fmaf(c.x, c.x, s0); s1 = fmaf(c.y, c.y, s1);
                s2 = fmaf(c.z, c.z, s2); s3 = fmaf(c.w, c.w, s3);
            }
            o[r] = (s0 + s1) + (s2 + s3);
        }
        cbt[u] = __builtin_bit_cast(short8, o);
    }
}

// 512 blocks x 512 thr (8 waves = 2 row-groups x 4 K-quarters), 128 rows
// per block, 64 rows/wave, exactly 2 blocks/CU. Phase 1: cooperative x ->
// bf16 hi/lo frags into LDS + ||x||^2 partials. Phase 2: wave (rg,kh) holds
// its 16 x-frags in 64 VGPR (resident under the 512-thr ~116 budget), scans
// tiles [kh*16,+16): 5 loads + 24 MFMA + min-track (b0,b1 reused for xl).
// Phase 3: shfl g-merge; waves 0-1 merge kh slices (ascending k tie-break),
// write idx/fidx/histogram/flag/SSE. Phase 4: all 8 waves gather qout from
// LDS fidx (coalesced 256B stores).
__global__ __launch_bounds__(512) void k_argmin(
        const float* __restrict__ in, const short8* __restrict__ cbt,
        const float* __restrict__ cb, int* __restrict__ idx,
        float* __restrict__ qout, unsigned* __restrict__ counts,
        unsigned* __restrict__ flagcnt, unsigned* __restrict__ flaglist,
        double* __restrict__ pblk) {
    __shared__ short8 xs[2][16][64];              // 32 KB
    __shared__ float rx2p[4][128];                // 2 KB
    __shared__ float sb[8][4][16], sb2[8][4][16];
    __shared__ int   sk[8][4][16];                // 6 KB
    __shared__ int   fidx[128];
    __shared__ double sred[2];

    const int tid = threadIdx.x;
    const int l = tid & 63;
    const int wid = tid >> 6;                     // 0..7
    const int g = l >> 4;
    const int col = l & 15;
    const int rowBase = blockIdx.x * 128;

    // Phase 1: thread (row=tid&127, ob=tid>>7) converts octs {ob, ob+4}
    // of its row; ll = ob*16 + (row&15), slot = rt*4 + hh (+2 for lo).
    {
        const int row = tid & 127;
        const int ob = tid >> 7;                  // 0..3
        const int rg = row >> 6;
        const int r6 = row & 63;
        const int rt = r6 >> 4;
        const int ll = ob * 16 + (r6 & 15);
        float part = 0.f;
#pragma unroll
        for (int hh = 0; hh < 2; ++hh) {
            const int oct = ob + hh * 4;
            short8 H, L;
#pragma unroll
            for (int j = 0; j < 8; ++j) {
                const float x = in[(size_t)(oct * 8 + j) * NR + rowBase + row];
                const unsigned short hb = bf16rne(x);
                H[j] = (short)hb;
                L[j] = (short)bf16rne(x - bf16tof(hb));
                part = fmaf(x, x, part);
            }
            xs[rg][rt * 4 + hh][ll] = H;
            xs[rg][rt * 4 + 2 + hh][ll] = L;
        }
        rx2p[ob][row] = part;
    }
    __syncthreads();

    // Phase 2: x frags to regs (resident), simple per-tile loop.
    const int rg = wid >> 2, kh = wid & 3;
    short8 xq[4][4];
#pragma unroll
    for (int rt = 0; rt < 4; ++rt)
#pragma unroll
        for (int q = 0; q < 4; ++q)
            xq[rt][q] = xs[rg][rt * 4 + q][l];

    float best[4]  = {3.4e38f, 3.4e38f, 3.4e38f, 3.4e38f};
    float best2[4] = {3.4e38f, 3.4e38f, 3.4e38f, 3.4e38f};
    int bestk[4] = {0, 0, 0, 0};

#pragma unroll 2
    for (int tt = 0; tt < 16; ++tt) {
        const int t = kh * 16 + tt;
        const short8* bp = cbt + (size_t)t * 320 + l;
        const short8 b0 = bp[0], b1 = bp[64], b2 = bp[128], b3 = bp[192];
        const f32x4 e4 = __builtin_bit_cast(f32x4, bp[256]);
#pragma unroll
        for (int rt = 0; rt < 4; ++rt) {
            f32x4 acc = e4;
            acc = __builtin_amdgcn_mfma_f32_16x16x32_bf16(b0, xq[rt][0], acc, 0, 0, 0);
            acc = __builtin_amdgcn_mfma_f32_16x16x32_bf16(b1, xq[rt][1], acc, 0, 0, 0);
            acc = __builtin_amdgcn_mfma_f32_16x16x32_bf16(b2, xq[rt][0], acc, 0, 0, 0);
            acc = __builtin_amdgcn_mfma_f32_16x16x32_bf16(b3, xq[rt][1], acc, 0, 0, 0);
            acc = __builtin_amdgcn_mfma_f32_16x16x32_bf16(b0, xq[rt][2], acc, 0, 0, 0);
            acc = __builtin_amdgcn_mfma_f32_16x16x32_bf16(b1, xq[rt][3], acc, 0, 0, 0);
#pragma unroll
            for (int r = 0; r < 4; ++r) {
                const float v = acc[r];
                const int k = t * 16 + g * 4 + r;
                best2[rt] = fminf(fmaxf(v, best[rt]), best2[rt]);  // med3
                const bool c = v < best[rt];
                bestk[rt] = c ? k : bestk[rt];
                best[rt]  = fminf(v, best[rt]);
            }
        }
    }

    // Phase 3a: intra-wave g-merge; g==0 writes per-(rg,kh) partials.
#pragma unroll
    for (int rt = 0; rt < 4; ++rt) {
        float b = best[rt], b2 = best2[rt]; int k = bestk[rt];
#pragma unroll
        for (int sh = 16; sh <= 32; sh <<= 1) {
            const float ob  = __shfl_xor(b, sh, 64);
            const float ob2 = __shfl_xor(b2, sh, 64);
            const int   ok  = __shfl_xor(k, sh, 64);
            if (ob < b || (ob == b && ok < k)) { b2 = fminf(b, ob2); k = ok; b = ob; }
            else b2 = fminf(b2, ob);
        }
        if (g == 0) { sb[wid][rt][col] = b; sb2[wid][rt][col] = b2; sk[wid][rt][col] = k; }
    }
    __syncthreads();

    // Phase 3b: waves 0-1 (rg=wid) merge the 4 kh slices; finalize rows.
    if (wid < 2) {
        const int rt = l >> 4, c2 = l & 15;
        float b = sb[wid * 4][rt][c2], b2 = sb2[wid * 4][rt][c2];
        int k = sk[wid * 4][rt][c2];
#pragma unroll
        for (int s = 1; s < 4; ++s) {              // ascending k ranges
            const float ob = sb[wid * 4 + s][rt][c2], ob2 = sb2[wid * 4 + s][rt][c2];
            const int ok = sk[wid * 4 + s][rt][c2];
            if (ob < b || (ob == b && ok < k)) { b2 = fminf(b, ob2); k = ok; b = ob; }
            else b2 = fminf(b2, ob);
        }
        const int lrow = wid * 64 + rt * 16 + c2;
        const int row = rowBase + lrow;
        idx[row] = k;
        fidx[lrow] = k;
        atomicAdd(&counts[k], 1u);
        if (b2 - b < GAP1) {
            const unsigned p = atomicAdd(flagcnt, 1u);
            flaglist[p] = (unsigned)row;
        }
        double d2 = (double)b + (double)((rx2p[0][lrow] + rx2p[1][lrow])
                                       + (rx2p[2][lrow] + rx2p[3][lrow]));
#pragma unroll
        for (int off = 32; off > 0; off >>= 1) d2 += __shfl_down(d2, off, 64);
        if (l == 0) sred[wid] = d2;
    }
    __syncthreads();
    if (tid == 0) pblk[blockIdx.x] = sred[0] + sred[1];

    // Phase 4: cooperative gather. thread -> (e-range e0*16.., row); lanes
    // cover 64 consecutive rows -> coalesced 256B stores per e.
    {
        const int row = tid & 127;
        const int e0 = tid >> 7;                  // 0..3
        const int k = fidx[row];
        const float4* c4 = (const float4*)(cb + (size_t)k * ED + e0 * 16);
#pragma unroll
        for (int j = 0; j < 4; ++j) {
            const float4 v = c4[j];
            qout[(size_t)(e0 * 16 + j * 4 + 0) * NR + rowBase + row] = v.x;
            qout[(size_t)(e0 * 16 + j * 4 + 1) * NR + rowBase + row] = v.y;
            qout[(size_t)(e0 * 16 + j * 4 + 2) * NR + rowBase + row] = v.z;
            qout[(size_t)(e0 * 16 + j * 4 + 3) * NR + rowBase + row] = v.w;
        }
    }
}

// fp64 exact argmin for flagged rows; one wave per row; adjusts histogram
// and rewrites the row's qout column when the index changes. (SSE delta
// < GAP1 per flipped row -> negligible.)
__global__ __launch_bounds__(256) void k_exact64(
        const float* __restrict__ in, const float* __restrict__ cb,
        int* __restrict__ idx, float* __restrict__ qout,
        unsigned* __restrict__ counts,
        const unsigned* __restrict__ flagcnt, const unsigned* __restrict__ flaglist) {
    const unsigned nf = *flagcnt;
    const int l = threadIdx.x & 63;
    const unsigned wave = blockIdx.x * 4u + (unsigned)(threadIdx.x >> 6);
    const unsigned nwave = gridDim.x * 4u;
    for (unsigned i = wave; i < nf; i += nwave) {
        const int row = (int)flaglist[i];
        float x[ED];
#pragma unroll
        for (int e = 0; e < ED; ++e) x[e] = in[(size_t)e * NR + row];
        double best = 1e300; int bestk = 0;
        for (int ci = 0; ci < 16; ++ci) {
            const int k = ci * 64 + l;              // ascending k per lane
            const float* c = cb + (size_t)k * ED;
            double s = 0.0, e2 = 0.0;
            for (int e = 0; e < ED; ++e) {
                const double cv = (double)c[e];
                e2 = fma(cv, cv, e2);
                s  = fma(cv, (double)x[e], s);
            }
            const double t = fma(-2.0, s, e2);
            if (t < best) { best = t; bestk = k; }
        }
        for (int sh = 1; sh < 64; sh <<= 1) {
            const double ob = __shfl_xor(best, sh, 64);
            const int   ok  = __shfl_xor(bestk, sh, 64);
            if (ob < best || (ob == best && ok < bestk)) { best = ob; bestk = ok; }
        }
        const int old = idx[row];                  // same addr all lanes
        if (bestk != old) {
            if (l == 0) {
                idx[row] = bestk;
                atomicSub(&counts[old], 1u);
                atomicAdd(&counts[bestk], 1u);
            }
            qout[(size_t)l * NR + row] = cb[(size_t)bestk * ED + l];
        }
    }
}

// Scalars: entropy from final counts + SSE from 512 per-block partials
// (fixed-order tree -> deterministic).
__global__ __launch_bounds__(1024) void k_final(const unsigned* __restrict__ counts,
        const double* __restrict__ pblk, float* __restrict__ out) {
    __shared__ double redE[16], redS[16];
    const int tid = threadIdx.x;
    const double p = (double)counts[tid] * (1.0 / 65536.0);
    double term = p * log(p + 1e-10);
    double s = (tid < 512) ? pblk[tid] : 0.0;
#pragma unroll
    for (int off = 32; off > 0; off >>= 1) {
        term += __shfl_down(term, off, 64);
        s    += __shfl_down(s,    off, 64);
    }
    if ((tid & 63) == 0) { redE[tid >> 6] = term; redS[tid >> 6] = s; }
    __syncthreads();
    if (tid == 0) {
        double e = 0.0, ss = 0.0;
        for (int i = 0; i < 16; ++i) { e += redE[i]; ss += redS[i]; }
        out[1 + NE] = (float)exp(-e);                 // perplexity
        const double m = ss * (1.0 / 4194304.0);      // mean((q-x)^2)
        out[0] = (float)(1.25 * m);                   // (1+beta)*m
    }
}

extern "C" void kernel_launch(void* const* d_in, const int* in_sizes, int n_in,
                              void* d_out, int out_size, void* d_ws, size_t ws_size,
                              hipStream_t stream) {
    (void)in_sizes; (void)n_in; (void)out_size; (void)ws_size;
    const float* in = (const float*)d_in[0];
    const float* cb = (const float*)d_in[1];
    float* out = (float*)d_out;

    // ws layout (dword offsets), strictly disjoint:
    //  [0,1024) counts | [1024] flagcnt
    //  [2048,83968)   cbt: 64 tiles x 320 short8 (compact 5KB records)
    //  [83968,149504) idx | [149504,215040) flaglist
    //  pblk: 512 f64 at byte 991232 (8B-aligned)
    unsigned* counts   = (unsigned*)d_ws;
    unsigned* flagcnt  = (unsigned*)d_ws + 1024;
    short8*   cbt      = (short8*)((float*)d_ws + 2048);
    int*      idx      = (int*)d_ws + 83968;
    unsigned* flaglist = (unsigned*)d_ws + 149504;
    double*   pblk     = (double*)((char*)d_ws + 991232);

    hipLaunchKernelGGL(k_pack,    dim3(80),  dim3(256),  0, stream,
                       cb, cbt, counts, flagcnt);
    hipLaunchKernelGGL(k_argmin,  dim3(512), dim3(512),  0, stream,
                       in, cbt, cb, idx, out + 1, counts, flagcnt, flaglist, pblk);
    hipLaunchKernelGGL(k_exact64, dim3(128), dim3(256),  0, stream,
                       in, cb, idx, out + 1, counts, flagcnt, flaglist);
    hipLaunchKernelGGL(k_final,   dim3(1),   dim3(1024), 0, stream,
                       counts, pblk, out);
}